// Round 8
// baseline (188.441 us; speedup 1.0000x reference)
//
#include <hip/hip_runtime.h>

// VACF via banded-Gram MFMA, round 17: XCD-pinned k-slices (L2-resident).
// G[t] = sum_i X[i][:] . X[i+t][:]  (t=0..99), X = [T=10000, C=3000] fp32.
//
// R16 post-mortem: vacf_fused ran 70us with ~0.8MB of HBM traffic --
// entirely L3-resident and STILL 70us. Cross-session invariant: every
// global-READ phase delivers 2.2-2.6 TB/s (R16: 185MB/70us) regardless of
// mechanism (gload_lds vs register), fan-out (8/4/1 segs/instr), MLP
// (4-144KB in flight/CU), occupancy, HBM residency. Writes hit 6.9 TB/s,
// L2 spec 34.5. Conclusion: ~2.5 TB/s is the Infinity-Cache READ-hit wall,
// and all our reads are L3 hits (X=120MB << 256MB L3 but >> 32MB L2;
// XCD round-robin kills L2 locality).
// R17: make reads L2-hits instead. Pin each 32-col k-slice (10000x32 fp32
// = 1.28MB < 4MB XCD-L2) to ONE XCD via dispatch residue:
//   xcd = blk&7, u = blk>>3, ksix = xcd + 8*(u/40), bb = u%40.
// bb cycles fastest -> slice read from HBM once, then 40 row-blocks (and
// the 128-row band overlap of consecutive bb) hit L2 at 34.5 TB/s.
// Concurrent footprint 3 blk/CU x 32 CU = 96 blocks ~ 2.4-3 slices =
// 3.1-3.8MB <= 4MB L2. KW 64->32 (KS=96, slices 94-95 all-zero = 2% waste),
// LDS 24.6KB, 4-slot sigma swizzle (write b64 + read b128 both exactly
// conflict-free by bank arithmetic), NPART 8->32 (atomic tail thinning).
// Predict: fused 70 -> 25-35us, FETCH 120-190MB real, total 186.7 -> ~145.
// Falsifier: fused unchanged -> XCD-mapping or L3-wall theory wrong ->
// next round probes with a minimal in-kernel ubench, not another variant.

#define T_DIM 10000
#define C_DIM 3000
#define W 100
#define MA 256               // A rows per block
#define NA 16                // A subblocks of 16
#define SROWS 384            // staged rows (A + 128-row band)
#define NBB 40               // 40*256 = 10240 >= 10000
#define KS 96                // col-slices (96*32 = 3072; 94,95 all-zero)
#define KW 32                // cols per slice (one MFMA K-chunk)
#define SPX 12               // slices per XCD (96/8)
#define NPART 32             // partial buckets (blk&31: 4 per XCD, XCD-local)

typedef __attribute__((ext_vector_type(8))) short short8;    // 8 bf16
typedef __attribute__((ext_vector_type(4))) short short4v;   // 4 bf16
typedef __attribute__((ext_vector_type(4))) float float4v;

__device__ __forceinline__ short f2bf(float f) {   // RNE fp32->bf16 (finite)
    unsigned u = __float_as_uint(f);
    u += 0x7fffu + ((u >> 16) & 1u);
    return (short)(u >> 16);
}

// ---------------------------------------------------------------------------
// Fused kernel. LDS row = 32 bf16 = 64 B = 4 slots of 16 B.
// sigma(row) = (row>>1)&3; phys slot = logical slot ^ sigma.
//   write: lane covers (row rr, cols 4*(lane&7)..+3) -> b64, conflict-free
//          (quarter-wave = 2 rows x 16 words = 32 words, banks 0..31 once).
//   read:  fragment row R=16a+n, logical slot quad -> b128, conflict-free
//          (16 lanes x 4 words = 64 words, 2/bank exactly).
// ---------------------------------------------------------------------------
__global__ __launch_bounds__(256, 3)
void vacf_fused(const float* __restrict__ X, float* __restrict__ partial) {
    const int tid  = threadIdx.x;
    const int lane = tid & 63;
    const int wv   = tid >> 6;
    const int xcd  = blockIdx.x & 7;
    const int u    = blockIdx.x >> 3;          // 0..479
    const int ksix = xcd + 8 * (u / NBB);      // slice: pinned to this XCD
    const int bb   = u % NBB;                  // row-block: cycles fastest
    const int i0   = bb * MA;
    const int c0   = ksix * KW;

    __shared__ __align__(16) char lds[SROWS * 64];   // 24.6 KB
    __shared__ float bins[W];
    if (tid < W) bins[tid] = 0.f;

    // staging map: iter m (0..11): row = m*32 + rr, cols cl..cl+3.
    // Wave-load = 8 rows x 128 B contiguous segments.
    const int rr = tid >> 3;          // 0..31
    const int cl = (tid & 7) * 4;     // 0..28
    // sigma(m*32+rr) = (rr>>1)&3 (m*32 == 0 mod 8 after >>1 mod 4)
    const int sw = ((((cl >> 3) ^ ((rr >> 1) & 3)) << 4) | ((cl & 7) << 1));

    const bool fast = (i0 + SROWS <= T_DIM) && (c0 + KW <= C_DIM);
    if (fast) {
        float4v v[12];
        #pragma unroll
        for (int m = 0; m < 12; ++m)
            v[m] = *(const float4v*)(X + (size_t)(i0 + m * 32 + rr) * C_DIM + c0 + cl);
        #pragma unroll
        for (int m = 0; m < 12; ++m) {
            short4v o;
            o[0] = f2bf(v[m][0]); o[1] = f2bf(v[m][1]);
            o[2] = f2bf(v[m][2]); o[3] = f2bf(v[m][3]);
            *(short4v*)&lds[(m * 32 + rr) * 64 + sw] = o;
        }
    } else {
        #pragma unroll
        for (int m = 0; m < 12; ++m) {
            const int row = m * 32 + rr;
            const int gr  = i0 + row;
            float4v v = {0.f, 0.f, 0.f, 0.f};
            if (gr < T_DIM && c0 + cl + 4 <= C_DIM)   // cols step 4, 3000%4==0
                v = *(const float4v*)(X + (size_t)gr * C_DIM + c0 + cl);
            short4v o;
            o[0] = f2bf(v[0]); o[1] = f2bf(v[1]);
            o[2] = f2bf(v[2]); o[3] = f2bf(v[3]);
            *(short4v*)&lds[row * 64 + sw] = o;
        }
    }
    __syncthreads();                          // tile ready (and bins init)

    // compute: acc0 = diagonal d0 tiles, acc1 = d0+1.
    const int n    = lane & 15;
    const int quad = lane >> 4;
    const int d0   = 2 * wv;

    float4v acc0 = {0.f, 0.f, 0.f, 0.f};
    float4v acc1 = {0.f, 0.f, 0.f, 0.f};

    const char* lb = lds + n * 64 + ((quad ^ ((n >> 1) & 3)) << 4);
    short8 fbp = *(const short8*)(lb + d0 * 1024);       // B subblock d0
    #pragma unroll
    for (int a = 0; a < NA; ++a) {
        const short8 fav = *(const short8*)(lb + a * 1024);
        const short8 fbn = *(const short8*)(lb + (d0 + a + 1) * 1024);
        acc0 = __builtin_amdgcn_mfma_f32_16x16x32_bf16(fav, fbp, acc0, 0, 0, 0);
        acc1 = __builtin_amdgcn_mfma_f32_16x16x32_bf16(fav, fbn, acc1, 0, 0, 0);
        fbp = fbn;
    }

    // epilogue: D[m][n] of diagonal d -> lag t = 16d + n - m  (m = quad*4 + p)
    #pragma unroll
    for (int p = 0; p < 4; ++p) {
        const int m  = quad * 4 + p;
        const int t0 = 16 * d0 + n - m;
        if (t0 >= 0 && t0 < W) atomicAdd(&bins[t0], acc0[p]);
        const int t1 = t0 + 16;
        if (t1 >= 0 && t1 < W) atomicAdd(&bins[t1], acc1[p]);
    }
    __syncthreads();
    if (tid < W) atomicAdd(&partial[(blockIdx.x & (NPART - 1)) * W + tid], bins[tid]);
}

__global__ void vacf_scale(const float* __restrict__ partial, float* __restrict__ out) {
    int t = threadIdx.x;
    if (t < W) {
        float s = 0.f;
        #pragma unroll
        for (int b = 0; b < NPART; ++b) s += partial[b * W + t];
        out[t] = s / ((float)(T_DIM - t) * (float)C_DIM);
    }
}

extern "C" void kernel_launch(void* const* d_in, const int* in_sizes, int n_in,
                              void* d_out, int out_size, void* d_ws, size_t ws_size,
                              hipStream_t stream) {
    const float* X = (const float*)d_in[0];
    float* out = (float*)d_out;
    float* ws  = (float*)d_ws;

    hipMemsetAsync(ws, 0, NPART * W * sizeof(float), stream);
    vacf_fused<<<KS * NBB, 256, 0, stream>>>(X, ws);
    vacf_scale<<<1, 128, 0, stream>>>(ws, out);
}